// Round 9
// baseline (644.372 us; speedup 1.0000x reference)
//
#include <hip/hip_runtime.h>
#include <hip/hip_fp16.h>
#include <cstdint>
#include <cstddef>

#define IN_DIM 128
#define HID    128
#define NG     20
#define T      4096        // edges per binsort1 block
#define MAXB   400         // max coarse bins (N <= 102400)

__global__ void zero_ints(int* __restrict__ a, int n) {
  int i = blockIdx.x * blockDim.x + threadIdx.x;
  if (i < n) a[i] = 0;
}

// ============ level 1: block-local sort into coarse bins (256 nodes/bin) ============
__global__ __launch_bounds__(256) void binsort1(const int* __restrict__ src,
    const int* __restrict__ dst, int* __restrict__ tmp, int* __restrict__ bofs,
    int* __restrict__ bintot, int NBC, int E) {
  __shared__ int lhist[MAXB];
  __shared__ int lscan[512];
  __shared__ int lcur[MAXB];
  __shared__ int sbuf[T];
  int tid = threadIdx.x;
  int tile0 = blockIdx.x * T;
  int m = E - tile0; if (m > T) m = T;

  for (int i = tid; i < NBC; i += 256) lhist[i] = 0;
  __syncthreads();

  int dreg[16];
#pragma unroll
  for (int j = 0; j < 16; ++j) {
    int idx = j * 256 + tid;
    dreg[j] = -1;
    if (idx < m) {
      int d = dst[tile0 + idx];
      dreg[j] = d;
      atomicAdd(&lhist[d >> 8], 1);
    }
  }
  __syncthreads();

  int v0 = (tid < NBC) ? lhist[tid] : 0;
  int v1 = (256 + tid < NBC) ? lhist[256 + tid] : 0;
  lscan[tid] = v0; lscan[256 + tid] = v1;
  __syncthreads();
  for (int o = 1; o < 512; o <<= 1) {
    int a0 = (tid >= o) ? lscan[tid - o] : 0;
    int a1 = (256 + tid >= o) ? lscan[256 + tid - o] : 0;
    __syncthreads();
    lscan[tid] += a0; lscan[256 + tid] += a1;
    __syncthreads();
  }
  if (tid < NBC)       lcur[tid]       = lscan[tid] - v0;
  if (256 + tid < NBC) lcur[256 + tid] = lscan[256 + tid] - v1;
  __syncthreads();

  int ST = NBC + 1;
  for (int i = tid; i < NBC; i += 256) bofs[(size_t)blockIdx.x * ST + i] = lcur[i];
  if (tid == 0) bofs[(size_t)blockIdx.x * ST + NBC] = m;
  for (int i = tid; i < NBC; i += 256)
    if (lhist[i]) atomicAdd(&bintot[i], lhist[i]);
  __syncthreads();

#pragma unroll
  for (int j = 0; j < 16; ++j) {
    int idx = j * 256 + tid;
    if (idx < m) {
      int d = dreg[j];
      int s = src[tile0 + idx];
      int slot = atomicAdd(&lcur[d >> 8], 1);
      sbuf[slot] = ((d & 255) << 17) | s;
    }
  }
  __syncthreads();

  int nv = m >> 2;
  int4* out4 = (int4*)(tmp + tile0);
  const int4* sb4 = (const int4*)sbuf;
  for (int i = tid; i < nv; i += 256) out4[i] = sb4[i];
  for (int i = (nv << 2) + tid; i < m; i += 256) tmp[tile0 + i] = sbuf[i];
}

// ============ scan bin totals -> bin bases (1 block) ============
__global__ __launch_bounds__(512) void binscan(const int* __restrict__ bintot,
                                               int* __restrict__ binbase, int NBC) {
  __shared__ int s[512];
  int tid = threadIdx.x;
  int v = (tid < NBC) ? bintot[tid] : 0;
  s[tid] = v;
  __syncthreads();
  for (int o = 1; o < 512; o <<= 1) {
    int t = (tid >= o) ? s[tid - o] : 0;
    __syncthreads();
    s[tid] += t;
    __syncthreads();
  }
  if (tid < NBC) binbase[tid] = s[tid] - v;
}

// ============ level 2: one block per coarse bin -> final CSR + node meta ============
__global__ __launch_bounds__(512) void binsort2(const int* __restrict__ tmp,
    const int* __restrict__ bofs, const int* __restrict__ binbase,
    int* __restrict__ csrc, int* __restrict__ cnt, float* __restrict__ dis,
    int* __restrict__ offs, int NBC, int nblk, int N) {
  __shared__ int lcnt[256];
  __shared__ int lsc[256];
  __shared__ int lcur2[256];
  int b = blockIdx.x;
  int tid = threadIdx.x;
  if (tid < 256) lcnt[tid] = 0;
  __syncthreads();
  int ST = NBC + 1;
  for (int r = tid; r < nblk; r += 512) {
    int s = bofs[(size_t)r * ST + b];
    int e2 = bofs[(size_t)r * ST + b + 1];
    int base = r * T;
    for (int k = s; k < e2; ++k)
      atomicAdd(&lcnt[tmp[base + k] >> 17], 1);
  }
  __syncthreads();
  if (tid < 256) lsc[tid] = lcnt[tid];
  __syncthreads();
  for (int o = 1; o < 256; o <<= 1) {
    int t = 0;
    if (tid < 256 && tid >= o) t = lsc[tid - o];
    __syncthreads();
    if (tid < 256) lsc[tid] += t;
    __syncthreads();
  }
  int gbase = binbase[b];
  if (tid < 256) {
    int excl = lsc[tid] - lcnt[tid];
    lcur2[tid] = gbase + excl;
    int node = (b << 8) + tid;
    if (node < N) {
      cnt[node] = lcnt[tid];
      dis[node] = rsqrtf((float)lcnt[tid] + 1.0f);
      offs[node] = gbase + excl;
    }
  }
  __syncthreads();
  for (int r = tid; r < nblk; r += 512) {
    int s = bofs[(size_t)r * ST + b];
    int e2 = bofs[(size_t)r * ST + b + 1];
    int base = r * T;
    for (int k = s; k < e2; ++k) {
      int rec = tmp[base + k];
      int pos = atomicAdd(&lcur2[rec >> 17], 1);
      csrc[pos] = rec & 0x1FFFF;
    }
  }
}

// ============ f32 GEMM, f16 split output: hA[M,64] = cols 0-63, hB[M,64] = cols 64-127 ======
#define MT 64
#define KC 64
__global__ __launch_bounds__(256) void gemm128_f16out(const float* __restrict__ A,
                                                      const float* __restrict__ B,
                                                      __half* __restrict__ CA,
                                                      __half* __restrict__ CB, int M) {
  __shared__ float sA[MT][KC + 4];
  __shared__ float sB[KC][128];
  int tid = threadIdx.x;
  int m0 = blockIdx.x * MT;
  int tr = tid >> 4;   // 0..15
  int tc = tid & 15;   // 0..15
  float acc[4][8];
#pragma unroll
  for (int i = 0; i < 4; ++i)
#pragma unroll
    for (int j = 0; j < 8; ++j) acc[i][j] = 0.f;

  for (int k0 = 0; k0 < 128; k0 += KC) {
#pragma unroll
    for (int q = 0; q < 4; ++q) {
      int idx = q * 256 + tid;
      int r = idx >> 4;
      int kk = (idx & 15) << 2;
      float4 v = make_float4(0.f, 0.f, 0.f, 0.f);
      if (m0 + r < M) v = *(const float4*)(A + (size_t)(m0 + r) * 128 + k0 + kk);
      *(float4*)(&sA[r][kk]) = v;
    }
#pragma unroll
    for (int q = 0; q < 8; ++q) {
      int idx = q * 256 + tid;
      int kk = idx >> 5;
      int nn = (idx & 31) << 2;
      *(float4*)(&sB[kk][nn]) = *(const float4*)(B + (size_t)(k0 + kk) * 128 + nn);
    }
    __syncthreads();
#pragma unroll 2
    for (int k = 0; k < KC; k += 4) {
      float4 a0 = *(const float4*)(&sA[tr][k]);
      float4 a1 = *(const float4*)(&sA[tr + 16][k]);
      float4 a2 = *(const float4*)(&sA[tr + 32][k]);
      float4 a3 = *(const float4*)(&sA[tr + 48][k]);
#pragma unroll
      for (int u = 0; u < 4; ++u) {
        float4 blo = *(const float4*)(&sB[k + u][tc * 4]);
        float4 bhi = *(const float4*)(&sB[k + u][64 + tc * 4]);
        float av[4] = {((const float*)&a0)[u], ((const float*)&a1)[u],
                       ((const float*)&a2)[u], ((const float*)&a3)[u]};
        float bl[8] = {blo.x, blo.y, blo.z, blo.w, bhi.x, bhi.y, bhi.z, bhi.w};
#pragma unroll
        for (int i = 0; i < 4; ++i)
#pragma unroll
          for (int j = 0; j < 8; ++j) acc[i][j] = fmaf(av[i], bl[j], acc[i][j]);
      }
    }
    __syncthreads();
  }
#pragma unroll
  for (int i = 0; i < 4; ++i) {
    int r = m0 + tr + 16 * i;
    if (r < M) {
      __half2 p0 = __floats2half2_rn(acc[i][0], acc[i][1]);
      __half2 p1 = __floats2half2_rn(acc[i][2], acc[i][3]);
      __half2 p2 = __floats2half2_rn(acc[i][4], acc[i][5]);
      __half2 p3 = __floats2half2_rn(acc[i][6], acc[i][7]);
      __half2* dA = (__half2*)(CA + (size_t)r * 64 + tc * 4);
      __half2* dB = (__half2*)(CB + (size_t)r * 64 + tc * 4);
      dA[0] = p0; dA[1] = p1;
      dB[0] = p2; dB[1] = p3;
    }
  }
}

// ============ aggregation v3: half-column pass, paired-edge lanes ============
// hh is [N,64] f16; lanes 0-31 process edge j, lanes 32-63 edge j+1; fold at end.
// bias pointer pre-offset by hx*64 at launch.
__global__ __launch_bounds__(256) void agg_half(const __half* __restrict__ hh,
    const int* __restrict__ csrc,
    const int* __restrict__ offs, const int* __restrict__ cnt,
    const float* __restrict__ dis, const float* __restrict__ bias,
    float* __restrict__ out, int hx, int n) {
  int wave = threadIdx.x >> 6;
  int lane = threadIdx.x & 63;
  int i = blockIdx.x * 4 + wave;
  if (i >= n) return;
  int low = lane & 31;
  int grp = lane >> 5;
  int c = low * 2;
  int start = offs[i];
  int m = cnt[i];
  float di = dis[i];
  float ax = 0.f, ay = 0.f;

  for (int base = 0; base < m; base += 64) {
    int mc = m - base; if (mc > 64) mc = 64;
    // stage 64 edges: coalesced index load + parallel dis gather
    int   sj = 0;
    float wj = 0.f;
    if (lane < mc) {
      sj = csrc[start + base + lane];
      wj = dis[sj] * di;
    }
    int j = 0;
    for (; j + 8 <= mc; j += 8) {
      int e0 = j + grp, e1 = j + 2 + grp, e2 = j + 4 + grp, e3 = j + 6 + grp;
      int   s0 = __shfl(sj, e0), s1 = __shfl(sj, e1);
      int   s2 = __shfl(sj, e2), s3 = __shfl(sj, e3);
      float w0 = __shfl(wj, e0), w1 = __shfl(wj, e1);
      float w2 = __shfl(wj, e2), w3 = __shfl(wj, e3);
      float2 h0 = __half22float2(*(const __half2*)(hh + (size_t)s0 * 64 + c));
      float2 h1 = __half22float2(*(const __half2*)(hh + (size_t)s1 * 64 + c));
      float2 h2 = __half22float2(*(const __half2*)(hh + (size_t)s2 * 64 + c));
      float2 h3 = __half22float2(*(const __half2*)(hh + (size_t)s3 * 64 + c));
      ax = fmaf(h0.x, w0, ax); ay = fmaf(h0.y, w0, ay);
      ax = fmaf(h1.x, w1, ax); ay = fmaf(h1.y, w1, ay);
      ax = fmaf(h2.x, w2, ax); ay = fmaf(h2.y, w2, ay);
      ax = fmaf(h3.x, w3, ax); ay = fmaf(h3.y, w3, ay);
    }
    for (; j < mc; j += 2) {
      int e0 = j + grp;                 // may equal mc on odd tail: wj there is 0
      int   s0 = __shfl(sj, e0);
      float w0 = __shfl(wj, e0);
      float2 h0 = __half22float2(*(const __half2*)(hh + (size_t)s0 * 64 + c));
      ax = fmaf(h0.x, w0, ax); ay = fmaf(h0.y, w0, ay);
    }
  }
  // fold the two edge-halves
  ax += __shfl_xor(ax, 32);
  ay += __shfl_xor(ay, 32);

  if (lane < 32) {
    float d2 = di * di;
    float2 hs = __half22float2(*(const __half2*)(hh + (size_t)i * 64 + c));
    float2 bv = *(const float2*)(bias + c);
    float vx = fmaf(hs.x, d2, ax) + bv.x;
    float vy = fmaf(hs.y, d2, ay) + bv.y;
    *(float2*)(out + (size_t)i * 128 + hx * 64 + c) =
        make_float2(fmaxf(vx, 0.f), fmaxf(vy, 0.f));
  }
}

// ============ heads: pack 3x[128,20] weights into [128,64] (cols 60..63 zero) ============
__global__ void pack_heads_w(const float* __restrict__ piW, const float* __restrict__ muW,
                             const float* __restrict__ lsW, float* __restrict__ W64) {
  int i = blockIdx.x * 256 + threadIdx.x;
  if (i >= 128 * 64) return;
  int k = i >> 6, j = i & 63;
  float v = 0.f;
  if (j < 20)      v = piW[k * 20 + j];
  else if (j < 40) v = muW[k * 20 + (j - 20)];
  else if (j < 60) v = lsW[k * 20 + (j - 40)];
  W64[i] = v;
}

// ============ heads GEMM: out60[M,64] = A[M,128] @ W64[128,64] ============
__global__ __launch_bounds__(256) void gemm_heads(const float* __restrict__ A,
                                                  const float* __restrict__ B,
                                                  float* __restrict__ C, int M) {
  __shared__ float sA[64][KC + 4];
  __shared__ float sB[KC][68];
  int tid = threadIdx.x;
  int m0 = blockIdx.x * 64;
  int tr = tid >> 4;   // 0..15
  int tc = tid & 15;   // 0..15
  float acc[4][4];
#pragma unroll
  for (int i = 0; i < 4; ++i)
#pragma unroll
    for (int j = 0; j < 4; ++j) acc[i][j] = 0.f;

  for (int k0 = 0; k0 < 128; k0 += KC) {
#pragma unroll
    for (int q = 0; q < 4; ++q) {
      int idx = q * 256 + tid;
      int r = idx >> 4;
      int kk = (idx & 15) << 2;
      float4 v = make_float4(0.f, 0.f, 0.f, 0.f);
      if (m0 + r < M) v = *(const float4*)(A + (size_t)(m0 + r) * 128 + k0 + kk);
      *(float4*)(&sA[r][kk]) = v;
    }
#pragma unroll
    for (int q = 0; q < 4; ++q) {
      int idx = q * 256 + tid;
      int kk = idx >> 4;
      int nn = (idx & 15) << 2;
      *(float4*)(&sB[kk][nn]) = *(const float4*)(B + (size_t)(k0 + kk) * 64 + nn);
    }
    __syncthreads();
#pragma unroll 4
    for (int k = 0; k < KC; k += 4) {
      float4 a0 = *(const float4*)(&sA[tr][k]);
      float4 a1 = *(const float4*)(&sA[tr + 16][k]);
      float4 a2 = *(const float4*)(&sA[tr + 32][k]);
      float4 a3 = *(const float4*)(&sA[tr + 48][k]);
#pragma unroll
      for (int u = 0; u < 4; ++u) {
        float4 b = *(const float4*)(&sB[k + u][tc * 4]);
        float av[4] = {((const float*)&a0)[u], ((const float*)&a1)[u],
                       ((const float*)&a2)[u], ((const float*)&a3)[u]};
#pragma unroll
        for (int i = 0; i < 4; ++i) {
          acc[i][0] = fmaf(av[i], b.x, acc[i][0]);
          acc[i][1] = fmaf(av[i], b.y, acc[i][1]);
          acc[i][2] = fmaf(av[i], b.z, acc[i][2]);
          acc[i][3] = fmaf(av[i], b.w, acc[i][3]);
        }
      }
    }
    __syncthreads();
  }
#pragma unroll
  for (int i = 0; i < 4; ++i) {
    int r = m0 + tr + 16 * i;
    if (r < M)
      *(float4*)(C + (size_t)r * 64 + tc * 4) =
          make_float4(acc[i][0], acc[i][1], acc[i][2], acc[i][3]);
  }
}

// ============ heads postpass: bias + softmax(20) + scatter ============
__global__ __launch_bounds__(256) void heads_post(const float* __restrict__ out60,
    const float* __restrict__ pib, const float* __restrict__ mub,
    const float* __restrict__ lsb, float* __restrict__ out, int n) {
  int wave = threadIdx.x >> 6, lane = threadIdx.x & 63;
  int node = blockIdx.x * 4 + wave;
  if (node >= n) return;
  float v = 0.f;
  if (lane < 60) {
    v = out60[(size_t)node * 64 + lane];
    v += (lane < 20) ? pib[lane] : (lane < 40) ? mub[lane - 20] : lsb[lane - 40];
  }
  float pv = (lane < 20) ? v : -__builtin_inff();
  float mx = pv;
  for (int o = 16; o > 0; o >>= 1) mx = fmaxf(mx, __shfl_down(mx, o, 32));
  mx = __shfl(mx, 0, 32);
  float ev = (lane < 20) ? expf(v - mx) : 0.f;
  float sm = ev;
  for (int o = 16; o > 0; o >>= 1) sm += __shfl_down(sm, o, 32);
  sm = __shfl(sm, 0, 32);

  size_t base = (size_t)n * NG;
  if (lane < 20)      out[(size_t)node * NG + lane] = ev / sm;
  else if (lane < 40) out[base + (size_t)node * NG + (lane - 20)] = v;
  else if (lane < 60) out[2 * base + (size_t)node * NG + (lane - 40)] = v;
}

extern "C" void kernel_launch(void* const* d_in, const int* in_sizes, int n_in,
                              void* d_out, int out_size, void* d_ws, size_t ws_size,
                              hipStream_t stream) {
  const float* x   = (const float*)d_in[0];
  const int*   ei  = (const int*)d_in[1];
  const float* W1  = (const float*)d_in[2];
  const float* b1  = (const float*)d_in[3];
  const float* W2  = (const float*)d_in[4];
  const float* b2  = (const float*)d_in[5];
  const float* piW = (const float*)d_in[6];
  const float* pib = (const float*)d_in[7];
  const float* muW = (const float*)d_in[8];
  const float* mub = (const float*)d_in[9];
  const float* lsW = (const float*)d_in[10];
  const float* lsb = (const float*)d_in[11];
  float* out = (float*)d_out;

  const int N = in_sizes[0] / IN_DIM;
  const int E = in_sizes[1] / 2;
  const int* src = ei;
  const int* dst = ei + E;

  const int NBC  = (N + 255) >> 8;          // 391 coarse bins
  const int nblk = (E + T - 1) / T;         // 782 level-1 blocks
  const int ST   = NBC + 1;

  // workspace layout (~70 MB)
  char* p = (char*)d_ws;
  // region H: hA[N,64] + hB[N,64] f16 during layers; out60 [N,64] f32 for heads
  char* regionH = p;                        p += (size_t)N * HID * sizeof(__half);
  __half* hA   = (__half*)regionH;
  __half* hB   = hA + (size_t)N * 64;
  float* out60 = (float*)regionH;
  char* regionR = p;
  size_t szR = (size_t)N * HID * sizeof(float);
  size_t szT = (size_t)E * sizeof(int);
  p += (szR > szT ? szR : szT);
  int*   tmp    = (int*)regionR;
  float* bufB   = (float*)regionR;
  int*   csrc   = (int*)p;                  p += (size_t)E * sizeof(int);
  int*   bofs   = (int*)p;                  p += (size_t)nblk * ST * sizeof(int);
  int*   bintot = (int*)p;                  p += (size_t)MAXB * sizeof(int);
  int*   binbase= (int*)p;                  p += (size_t)MAXB * sizeof(int);
  int*   cnt    = (int*)p;                  p += (size_t)N * sizeof(int);
  int*   offs   = (int*)p;                  p += (size_t)N * sizeof(int);
  float* dis    = (float*)p;                p += (size_t)N * sizeof(float);
  float* W64    = (float*)p;                p += (size_t)128 * 64 * sizeof(float);

  // ---- CSR build ----
  zero_ints<<<(NBC + 255) / 256, 256, 0, stream>>>(bintot, NBC);
  binsort1<<<nblk, 256, 0, stream>>>(src, dst, tmp, bofs, bintot, NBC, E);
  binscan<<<1, 512, 0, stream>>>(bintot, binbase, NBC);
  binsort2<<<NBC, 512, 0, stream>>>(tmp, bofs, binbase, csrc, cnt, dis, offs,
                                    NBC, nblk, N);
  pack_heads_w<<<(128 * 64 + 255) / 256, 256, 0, stream>>>(piW, muW, lsW, W64);

  // ---- layers (agg split into two half-column passes, sequential for L2 locality) ----
  gemm128_f16out<<<(N + MT - 1) / MT, 256, 0, stream>>>(x, W1, hA, hB, N);
  agg_half<<<(N + 3) / 4, 256, 0, stream>>>(hA, csrc, offs, cnt, dis, b1,      bufB, 0, N);
  agg_half<<<(N + 3) / 4, 256, 0, stream>>>(hB, csrc, offs, cnt, dis, b1 + 64, bufB, 1, N);
  gemm128_f16out<<<(N + MT - 1) / MT, 256, 0, stream>>>(bufB, W2, hA, hB, N);
  agg_half<<<(N + 3) / 4, 256, 0, stream>>>(hA, csrc, offs, cnt, dis, b2,      bufB, 0, N);
  agg_half<<<(N + 3) / 4, 256, 0, stream>>>(hB, csrc, offs, cnt, dis, b2 + 64, bufB, 1, N);

  // ---- heads ----
  gemm_heads<<<(N + 63) / 64, 256, 0, stream>>>(bufB, W64, out60, N);
  heads_post<<<(N + 3) / 4, 256, 0, stream>>>(out60, pib, mub, lsb, out, N);
}